// Round 5
// baseline (154.903 us; speedup 1.0000x reference)
//
#include <hip/hip_runtime.h>

#define B_ROWS 2048
#define S_LEN  8192
#define PER_LANE 16
#define TPB 512
#define WPB 8                          // waves per block
#define CHUNK (64 * PER_LANE)          // 1024 elements per wave
#define NBLOCKS B_ROWS                 // one row per block; 8 waves cover 8192

// ---- compile-time decay constants ----
constexpr double cpowi(double b, int e) { double r = 1.0; for (int i = 0; i < e; ++i) r *= b; return r; }
constexpr float tof(double x) { return (x < 1.2e-38 && x > -1.2e-38) ? 0.0f : (float)x; }

// u-space EMA: u = ema / alpha, update u' = W*u + x  (W = 1 - alpha)
#define W0f 0.9f
#define W1f 0.7f
#define W2f 0.4f
#define IA0 10.0f              // 1/alpha
#define IA1 (1.0f / 0.3f)
#define IA2 (1.0f / 0.6f)
#define SE0 0.2f               // 2*alpha (huber accumulates 2*h; 0.5 folded into final weights)
#define SE1 0.6f
#define SE2 1.2f
constexpr float NA0 = -(0.1f * 0.1f);   // -alpha^2
constexpr float NA1 = -(0.3f * 0.3f);
constexpr float NA2 = -(0.6f * 0.6f);

// Kogge-Stone decays D^(16*2^k), D=(1-alpha); sub-half-ulp steps pruned.
constexpr float D0_1 = tof(cpowi(0.9, 16)),  D0_2 = tof(cpowi(0.9, 32));
constexpr float D0_4 = tof(cpowi(0.9, 64)),  D0_8 = tof(cpowi(0.9, 128));
constexpr float D1_1 = tof(cpowi(0.7, 16)),  D1_2 = tof(cpowi(0.7, 32));
constexpr float D2_1 = tof(cpowi(0.4, 16));

// log2(1-alpha): carry weights (1-a)^(16*lane) = exp2(16*lane*log2(1-a))
#define L2_0 (-0.15200309344504997f)
#define L2_1 (-0.51457317282975830f)
#define L2_2 (-1.32192809488736230f)

__device__ __forceinline__ float scan4(float v, int lane, float d1, float d2, float d4, float d8) {
    float u;
    u = __shfl_up(v, 1); v += (lane >= 1 ? d1 : 0.0f) * u;
    u = __shfl_up(v, 2); v += (lane >= 2 ? d2 : 0.0f) * u;
    u = __shfl_up(v, 4); v += (lane >= 4 ? d4 : 0.0f) * u;
    u = __shfl_up(v, 8); v += (lane >= 8 ? d8 : 0.0f) * u;
    return v;
}
__device__ __forceinline__ float scan2(float v, int lane, float d1, float d2) {
    float u;
    u = __shfl_up(v, 1); v += (lane >= 1 ? d1 : 0.0f) * u;
    u = __shfl_up(v, 2); v += (lane >= 2 ? d2 : 0.0f) * u;
    return v;
}
__device__ __forceinline__ float scan1(float v, int lane, float d1) {
    float u;
    u = __shfl_up(v, 1); v += (lane >= 1 ? d1 : 0.0f) * u;
    return v;
}

__global__ void __launch_bounds__(TPB, 8) msl_main(const float* __restrict__ pred,
                                                   const float* __restrict__ targ,
                                                   float* __restrict__ partial) {
    const int lane = threadIdx.x & 63;
    const int wave = threadIdx.x >> 6;
    const float* __restrict__ prow = pred + (size_t)blockIdx.x * S_LEN;
    const float* __restrict__ trow = targ + (size_t)blockIdx.x * S_LEN;
    const int base = wave * CHUNK + lane * PER_LANE;

    const bool w0   = (wave == 0);
    const bool lz   = (lane == 0);
    const bool head = w0 && lz;   // owns global element 0

    // ---- load #1: consumed entirely by pass 1, then dead (no fight with the
    // allocator -- r2/r3/r4 proved it refuses to keep x resident across the
    // barrier, paying a serialized reload after it instead). ----
    float xp[PER_LANE], xt[PER_LANE];
    {
        const float4* p4 = reinterpret_cast<const float4*>(prow + base);
        const float4* t4 = reinterpret_cast<const float4*>(trow + base);
#pragma unroll
        for (int j = 0; j < PER_LANE / 4; ++j) {
            float4 a = p4[j];
            float4 b = t4[j];
            xp[4 * j + 0] = a.x; xp[4 * j + 1] = a.y; xp[4 * j + 2] = a.z; xp[4 * j + 3] = a.w;
            xt[4 * j + 0] = b.x; xt[4 * j + 1] = b.y; xt[4 * j + 2] = b.z; xt[4 * j + 3] = b.w;
        }
    }

    // ---- pass 1: lane-local EMA in u-space, zero carry-in.
    // head: u_init = x0/a; its j=0 update W*(x0/a)+x0 == x0/a, matching pe[0]=x[0]. ----
    float Mp0 = head ? xp[0] * IA0 : 0.0f;
    float Mp1 = head ? xp[0] * IA1 : 0.0f;
    float Mp2 = head ? xp[0] * IA2 : 0.0f;
    float Mt0 = head ? xt[0] * IA0 : 0.0f;
    float Mt1 = head ? xt[0] * IA1 : 0.0f;
    float Mt2 = head ? xt[0] * IA2 : 0.0f;
#pragma unroll
    for (int j = 0; j < PER_LANE; ++j) {
        Mp0 = fmaf(W0f, Mp0, xp[j]);
        Mp1 = fmaf(W1f, Mp1, xp[j]);
        Mp2 = fmaf(W2f, Mp2, xp[j]);
        Mt0 = fmaf(W0f, Mt0, xt[j]);
        Mt1 = fmaf(W1f, Mt1, xt[j]);
        Mt2 = fmaf(W2f, Mt2, xt[j]);
    }

    // ---- load #2: explicit early re-load through a laundered pointer.
    // The opaque address blocks CSE-with-load#1 AND rematerialization, so these
    // 32 floats MUST live in VGPRs from here to pass 2. Issued ~13 shuffle-scan
    // rounds + LDS exchange before the barrier's vmcnt(0) drain -> the ~200 cy
    // L2-hit latency is fully covered instead of serializing after the barrier. ----
    unsigned long long ap = (unsigned long long)(prow + base);
    unsigned long long at = (unsigned long long)(trow + base);
    asm volatile("" : "+v"(ap), "+v"(at));
    float xq[PER_LANE], xu[PER_LANE];
    {
        const float4* q4 = reinterpret_cast<const float4*>(ap);
        const float4* u4 = reinterpret_cast<const float4*>(at);
        __builtin_amdgcn_sched_barrier(0);
#pragma unroll
        for (int j = 0; j < PER_LANE / 4; ++j) {
            float4 a = q4[j];
            float4 b = u4[j];
            xq[4 * j + 0] = a.x; xq[4 * j + 1] = a.y; xq[4 * j + 2] = a.z; xq[4 * j + 3] = a.w;
            xu[4 * j + 0] = b.x; xu[4 * j + 1] = b.y; xu[4 * j + 2] = b.z; xu[4 * j + 3] = b.w;
        }
        __builtin_amdgcn_sched_barrier(0);
    }

    // ---- wave scans (pruned per decay rate); loads #2 in flight underneath ----
    float vp0 = scan4(Mp0, lane, D0_1, D0_2, D0_4, D0_8);
    float vp1 = scan2(Mp1, lane, D1_1, D1_2);
    float vp2 = scan1(Mp2, lane, D2_1);
    float vt0 = scan4(Mt0, lane, D0_1, D0_2, D0_4, D0_8);
    float vt1 = scan2(Mt1, lane, D1_1, D1_2);
    float vt2 = scan1(Mt2, lane, D2_1);

    // ---- publish chunk-exit states (u-space). (1-a)^1024 == 0.0f exactly,
    // so exits are carry-in independent. ----
    __shared__ float sex[WPB][6];
    if (lane == 63) {
        sex[wave][0] = vp0; sex[wave][1] = vp1; sex[wave][2] = vp2;
        sex[wave][3] = vt0; sex[wave][4] = vt1; sex[wave][5] = vt2;
    }
    __syncthreads();

    float Cp0 = 0.f, Cp1 = 0.f, Cp2 = 0.f, Ct0 = 0.f, Ct1 = 0.f, Ct2 = 0.f;
    if (wave > 0) {
        Cp0 = sex[wave - 1][0]; Cp1 = sex[wave - 1][1]; Cp2 = sex[wave - 1][2];
        Ct0 = sex[wave - 1][3]; Ct1 = sex[wave - 1][4]; Ct2 = sex[wave - 1][5];
    }

    // analytic carry fold-in: exclusive carry y_l = v_{l-1} + (1-a)^(16*l) * C
    const float e  = (float)(PER_LANE * lane);
    const float G0 = exp2f(e * L2_0);
    const float G1 = exp2f(e * L2_1);
    const float G2 = exp2f(e * L2_2);

    float up0 = __shfl_up(vp0, 1), up1 = __shfl_up(vp1, 1), up2 = __shfl_up(vp2, 1);
    float ut0 = __shfl_up(vt0, 1), ut1 = __shfl_up(vt1, 1), ut2 = __shfl_up(vt2, 1);

    float yp0 = lz ? (w0 ? xq[0] * IA0 : Cp0) : fmaf(G0, Cp0, up0);
    float yp1 = lz ? (w0 ? xq[0] * IA1 : Cp1) : fmaf(G1, Cp1, up1);
    float yp2 = lz ? (w0 ? xq[0] * IA2 : Cp2) : fmaf(G2, Cp2, up2);
    float yt0 = lz ? (w0 ? xu[0] * IA0 : Ct0) : fmaf(G0, Ct0, ut0);
    float yt1 = lz ? (w0 ? xu[0] * IA1 : Ct1) : fmaf(G1, Ct1, ut1);
    float yt2 = lz ? (w0 ? xu[0] * IA2 : Ct2) : fmaf(G2, Ct2, ut2);

    // ---- pass 2: replay in u-space with exact carry; huber on scaled deltas.
    // pd = a*du_p, td = a*du_t:  dir<0 <=> dup*dut<0 ; se = a|dup-dut| ;
    // quad = 0.5*max(1 - a^2*dup*dut, 0)^2. Accumulate 2*h, weight 0.5 later. ----
    float acc0 = 0.f, acc1 = 0.f, acc2 = 0.f;
    const float skip = head ? 0.0f : 1.0f;  // no loss term for global t=0
#pragma unroll
    for (int j = 0; j < PER_LANE; ++j) {
        float n, dup0, dut0, dup1, dut1, dup2, dut2;
        n = fmaf(W0f, yp0, xq[j]); dup0 = n - yp0; yp0 = n;
        n = fmaf(W0f, yt0, xu[j]); dut0 = n - yt0; yt0 = n;
        n = fmaf(W1f, yp1, xq[j]); dup1 = n - yp1; yp1 = n;
        n = fmaf(W1f, yt1, xu[j]); dut1 = n - yt1; yt1 = n;
        n = fmaf(W2f, yp2, xq[j]); dup2 = n - yp2; yp2 = n;
        n = fmaf(W2f, yt2, xu[j]); dut2 = n - yt2; yt2 = n;

        float m0 = dup0 * dut0, m1 = dup1 * dut1, m2 = dup2 * dut2;
        float se0 = SE0 * fabsf(dup0 - dut0);
        float se1 = SE1 * fabsf(dup1 - dut1);
        float se2 = SE2 * fabsf(dup2 - dut2);
        float mm0 = fmaxf(fmaf(NA0, m0, 1.0f), 0.0f);
        float mm1 = fmaxf(fmaf(NA1, m1, 1.0f), 0.0f);
        float mm2 = fmaxf(fmaf(NA2, m2, 1.0f), 0.0f);
        float h0 = (m0 < 0.0f) ? se0 : mm0 * mm0;
        float h1 = (m1 < 0.0f) ? se1 : mm1 * mm1;
        float h2 = (m2 < 0.0f) ? se2 : mm2 * mm2;
        if (j == 0) { h0 *= skip; h1 *= skip; h2 *= skip; }
        acc0 += h0; acc1 += h1; acc2 += h2;
    }

    // accumulated 2*h -> weights are 0.5*{0.5,0.3,0.2}
    float wacc = 0.25f * acc0 + 0.15f * acc1 + 0.10f * acc2;
#pragma unroll
    for (int o = 32; o > 0; o >>= 1) wacc += __shfl_down(wacc, o);

    __shared__ float sred[WPB];
    if (lz) sred[wave] = wacc;
    __syncthreads();
    if (threadIdx.x == 0) {
        float s = 0.f;
#pragma unroll
        for (int i = 0; i < WPB; ++i) s += sred[i];
        partial[blockIdx.x] = s;
    }
}

__global__ void __launch_bounds__(256) msl_reduce(const float* __restrict__ partial,
                                                  float* __restrict__ out) {
    const int tid = threadIdx.x;
    float v = 0.f;
#pragma unroll
    for (int k = 0; k < NBLOCKS / 256; ++k) v += partial[tid + 256 * k];
#pragma unroll
    for (int o = 32; o > 0; o >>= 1) v += __shfl_down(v, o);
    __shared__ float s[4];
    if ((tid & 63) == 0) s[tid >> 6] = v;
    __syncthreads();
    if (tid == 0)
        out[0] = (s[0] + s[1] + s[2] + s[3]) *
                 (float)(1.0 / ((double)(S_LEN - 1) * (double)B_ROWS));
}

extern "C" void kernel_launch(void* const* d_in, const int* in_sizes, int n_in,
                              void* d_out, int out_size, void* d_ws, size_t ws_size,
                              hipStream_t stream) {
    const float* pred = (const float*)d_in[0];
    const float* targ = (const float*)d_in[1];
    float* out = (float*)d_out;
    float* partial = (float*)d_ws;  // 2048 floats = 8 KB

    msl_main<<<NBLOCKS, TPB, 0, stream>>>(pred, targ, partial);
    msl_reduce<<<1, 256, 0, stream>>>(partial, out);
}

// Round 6
// 143.939 us; speedup vs baseline: 1.0762x; 1.0762x over previous
//
#include <hip/hip_runtime.h>

#define B_ROWS 2048
#define S_LEN  8192
#define PER_LANE 16
#define TPB 512
#define WPB 8                          // waves per block
#define CHUNK (64 * PER_LANE)          // 1024 elements per wave
#define NBLOCKS B_ROWS                 // one row per block

// ---- compile-time decay constants ----
constexpr double cpowi(double b, int e) { double r = 1.0; for (int i = 0; i < e; ++i) r *= b; return r; }
constexpr float tof(double x) { return (x < 1.2e-38 && x > -1.2e-38) ? 0.0f : (float)x; }

// Delta-space EMA: du_j = W*du_{j-1} + dx_j  (W = 1-alpha), pd = alpha*du.
#define W0f 0.9f
#define W1f 0.7f
#define W2f 0.4f
#define SE0 0.2f               // 2*alpha (we accumulate 2*h; 0.5 folded into final weights)
#define SE1 0.6f
#define SE2 1.2f
constexpr float NA0 = -(0.1f * 0.1f);   // -alpha^2
constexpr float NA1 = -(0.3f * 0.3f);
constexpr float NA2 = -(0.6f * 0.6f);

// Kogge-Stone decays D^(16*2^k); sub-half-ulp steps pruned (same weights apply
// to the du recurrence -- it is the same linear recurrence, different input).
constexpr float D0_1 = tof(cpowi(0.9, 16)),  D0_2 = tof(cpowi(0.9, 32));
constexpr float D0_4 = tof(cpowi(0.9, 64)),  D0_8 = tof(cpowi(0.9, 128));
constexpr float D1_1 = tof(cpowi(0.7, 16)),  D1_2 = tof(cpowi(0.7, 32));
constexpr float D2_1 = tof(cpowi(0.4, 16));

// log2(1-alpha): carry weights (1-a)^(16*lane) = exp2(16*lane*log2(1-a))
#define L2_0 (-0.15200309344504997f)
#define L2_1 (-0.51457317282975830f)
#define L2_2 (-1.32192809488736230f)

__device__ __forceinline__ float scan4(float v, int lane, float d1, float d2, float d4, float d8) {
    float u;
    u = __shfl_up(v, 1); v += (lane >= 1 ? d1 : 0.0f) * u;
    u = __shfl_up(v, 2); v += (lane >= 2 ? d2 : 0.0f) * u;
    u = __shfl_up(v, 4); v += (lane >= 4 ? d4 : 0.0f) * u;
    u = __shfl_up(v, 8); v += (lane >= 8 ? d8 : 0.0f) * u;
    return v;
}
__device__ __forceinline__ float scan2(float v, int lane, float d1, float d2) {
    float u;
    u = __shfl_up(v, 1); v += (lane >= 1 ? d1 : 0.0f) * u;
    u = __shfl_up(v, 2); v += (lane >= 2 ? d2 : 0.0f) * u;
    return v;
}
__device__ __forceinline__ float scan1(float v, int lane, float d1) {
    float u;
    u = __shfl_up(v, 1); v += (lane >= 1 ? d1 : 0.0f) * u;
    return v;
}

__global__ void __launch_bounds__(TPB, 4) msl_main(const float* __restrict__ pred,
                                                   const float* __restrict__ targ,
                                                   float* __restrict__ partial) {
    const int lane = threadIdx.x & 63;
    const int wave = threadIdx.x >> 6;
    const float* __restrict__ prow = pred + (size_t)blockIdx.x * S_LEN;
    const float* __restrict__ trow = targ + (size_t)blockIdx.x * S_LEN;
    const int base = wave * CHUNK + lane * PER_LANE;

    // dx scratch: per-thread write+read (no barrier between them needed), laid
    // out [wave][arr][j][lane] so a wave's access at fixed j is lane-consecutive
    // 4B -> 2 lanes/bank (free on 32-bank LDS). This replaces the cross-barrier
    // register residency the allocator refused to grant in r2-r5.
    __shared__ float dxs[WPB][2][PER_LANE][64];   // 64 KB
    __shared__ float sex[WPB][6];
    __shared__ float sred[WPB];

    const bool w0 = (wave == 0);
    const bool lz = (lane == 0);

    // lane-0 (non-head) needs the element preceding its chunk; issue first.
    float pv0p = 0.f, pv0t = 0.f;
    if (lz && wave > 0) { pv0p = prow[base - 1]; pv0t = trow[base - 1]; }

    float xp[PER_LANE], xt[PER_LANE];
    {
        const float4* p4 = reinterpret_cast<const float4*>(prow + base);
        const float4* t4 = reinterpret_cast<const float4*>(trow + base);
#pragma unroll
        for (int j = 0; j < PER_LANE / 4; ++j) {
            float4 a = p4[j];
            float4 b = t4[j];
            xp[4 * j + 0] = a.x; xp[4 * j + 1] = a.y; xp[4 * j + 2] = a.z; xp[4 * j + 3] = a.w;
            xt[4 * j + 0] = b.x; xt[4 * j + 1] = b.y; xt[4 * j + 2] = b.z; xt[4 * j + 3] = b.w;
        }
    }

    // previous element for dx_0: lane l gets lane l-1's last element via shfl;
    // lane 0 uses the loaded prow[base-1]; global head uses x0 (dx_0 = 0, and
    // with zero carry the head's du_0 = 0 -- exactly the reference seed).
    float pvp = __shfl_up(xp[PER_LANE - 1], 1);
    float pvt = __shfl_up(xt[PER_LANE - 1], 1);
    if (lz) {
        pvp = w0 ? xp[0] : pv0p;
        pvt = w0 ? xt[0] : pv0t;
    }

    // ---- single consumption of x: dx, stage dx, lane-local du-EMA (zero carry) ----
    float Mp0 = 0.f, Mp1 = 0.f, Mp2 = 0.f, Mt0 = 0.f, Mt1 = 0.f, Mt2 = 0.f;
    float prevp = pvp, prevt = pvt;
#pragma unroll
    for (int j = 0; j < PER_LANE; ++j) {
        float dxp = xp[j] - prevp; prevp = xp[j];
        float dxt = xt[j] - prevt; prevt = xt[j];
        dxs[wave][0][j][lane] = dxp;
        dxs[wave][1][j][lane] = dxt;
        Mp0 = fmaf(W0f, Mp0, dxp);
        Mp1 = fmaf(W1f, Mp1, dxp);
        Mp2 = fmaf(W2f, Mp2, dxp);
        Mt0 = fmaf(W0f, Mt0, dxt);
        Mt1 = fmaf(W1f, Mt1, dxt);
        Mt2 = fmaf(W2f, Mt2, dxt);
    }
    // x is dead from here on -- nothing fights the allocator across the barrier.

    // ---- wave scans (pruned per decay rate): inclusive du at each lane's end ----
    float vp0 = scan4(Mp0, lane, D0_1, D0_2, D0_4, D0_8);
    float vp1 = scan2(Mp1, lane, D1_1, D1_2);
    float vp2 = scan1(Mp2, lane, D2_1);
    float vt0 = scan4(Mt0, lane, D0_1, D0_2, D0_4, D0_8);
    float vt1 = scan2(Mt1, lane, D1_1, D1_2);
    float vt2 = scan1(Mt2, lane, D2_1);

    // ---- publish chunk-exit du (carry-in independent: (1-a)^1024 == 0.0f) ----
    if (lane == 63) {
        sex[wave][0] = vp0; sex[wave][1] = vp1; sex[wave][2] = vp2;
        sex[wave][3] = vt0; sex[wave][4] = vt1; sex[wave][5] = vt2;
    }
    __syncthreads();

    float Cp0 = 0.f, Cp1 = 0.f, Cp2 = 0.f, Ct0 = 0.f, Ct1 = 0.f, Ct2 = 0.f;
    if (wave > 0) {
        Cp0 = sex[wave - 1][0]; Cp1 = sex[wave - 1][1]; Cp2 = sex[wave - 1][2];
        Ct0 = sex[wave - 1][3]; Ct1 = sex[wave - 1][4]; Ct2 = sex[wave - 1][5];
    }

    // exclusive carry: y_l = v_{l-1} + (1-a)^(16*l) * C   (head: 0)
    const float e  = (float)(PER_LANE * lane);
    const float G0 = exp2f(e * L2_0);
    const float G1 = exp2f(e * L2_1);
    const float G2 = exp2f(e * L2_2);

    float up0 = __shfl_up(vp0, 1), up1 = __shfl_up(vp1, 1), up2 = __shfl_up(vp2, 1);
    float ut0 = __shfl_up(vt0, 1), ut1 = __shfl_up(vt1, 1), ut2 = __shfl_up(vt2, 1);

    float yp0 = lz ? (w0 ? 0.0f : Cp0) : fmaf(G0, Cp0, up0);
    float yp1 = lz ? (w0 ? 0.0f : Cp1) : fmaf(G1, Cp1, up1);
    float yp2 = lz ? (w0 ? 0.0f : Cp2) : fmaf(G2, Cp2, up2);
    float yt0 = lz ? (w0 ? 0.0f : Ct0) : fmaf(G0, Ct0, ut0);
    float yt1 = lz ? (w0 ? 0.0f : Ct1) : fmaf(G1, Ct1, ut1);
    float yt2 = lz ? (w0 ? 0.0f : Ct2) : fmaf(G2, Ct2, ut2);

    // ---- pass 2: du = fma(W, du, dx) IS the delta; huber directly on it.
    // pd = a*du_p, td = a*du_t: dir<0 <=> dup*dut<0 ; se = a|dup-dut| ;
    // quad = 0.5*max(1 - a^2*dup*dut, 0)^2. Accumulate 2*h. ----
    float acc0 = 0.f, acc1 = 0.f, acc2 = 0.f;
    const float skip = (w0 && lz) ? 0.0f : 1.0f;  // no loss term for global t=0
#pragma unroll
    for (int j = 0; j < PER_LANE; ++j) {
        float dxp = dxs[wave][0][j][lane];
        float dxt = dxs[wave][1][j][lane];
        yp0 = fmaf(W0f, yp0, dxp);
        yt0 = fmaf(W0f, yt0, dxt);
        yp1 = fmaf(W1f, yp1, dxp);
        yt1 = fmaf(W1f, yt1, dxt);
        yp2 = fmaf(W2f, yp2, dxp);
        yt2 = fmaf(W2f, yt2, dxt);

        float m0 = yp0 * yt0, m1 = yp1 * yt1, m2 = yp2 * yt2;
        float se0 = SE0 * fabsf(yp0 - yt0);
        float se1 = SE1 * fabsf(yp1 - yt1);
        float se2 = SE2 * fabsf(yp2 - yt2);
        float mm0 = fmaxf(fmaf(NA0, m0, 1.0f), 0.0f);
        float mm1 = fmaxf(fmaf(NA1, m1, 1.0f), 0.0f);
        float mm2 = fmaxf(fmaf(NA2, m2, 1.0f), 0.0f);
        float h0 = (m0 < 0.0f) ? se0 : mm0 * mm0;
        float h1 = (m1 < 0.0f) ? se1 : mm1 * mm1;
        float h2 = (m2 < 0.0f) ? se2 : mm2 * mm2;
        if (j == 0) { h0 *= skip; h1 *= skip; h2 *= skip; }
        acc0 += h0; acc1 += h1; acc2 += h2;
    }

    // accumulated 2*h -> weights are 0.5*{0.5,0.3,0.2}
    float wacc = 0.25f * acc0 + 0.15f * acc1 + 0.10f * acc2;
#pragma unroll
    for (int o = 32; o > 0; o >>= 1) wacc += __shfl_down(wacc, o);

    if (lz) sred[wave] = wacc;
    __syncthreads();
    if (threadIdx.x == 0) {
        float s = 0.f;
#pragma unroll
        for (int i = 0; i < WPB; ++i) s += sred[i];
        partial[blockIdx.x] = s;
    }
}

__global__ void __launch_bounds__(256) msl_reduce(const float* __restrict__ partial,
                                                  float* __restrict__ out) {
    const int tid = threadIdx.x;
    float v = 0.f;
#pragma unroll
    for (int k = 0; k < NBLOCKS / 256; ++k) v += partial[tid + 256 * k];
#pragma unroll
    for (int o = 32; o > 0; o >>= 1) v += __shfl_down(v, o);
    __shared__ float s[4];
    if ((tid & 63) == 0) s[tid >> 6] = v;
    __syncthreads();
    if (tid == 0)
        out[0] = (s[0] + s[1] + s[2] + s[3]) *
                 (float)(1.0 / ((double)(S_LEN - 1) * (double)B_ROWS));
}

extern "C" void kernel_launch(void* const* d_in, const int* in_sizes, int n_in,
                              void* d_out, int out_size, void* d_ws, size_t ws_size,
                              hipStream_t stream) {
    const float* pred = (const float*)d_in[0];
    const float* targ = (const float*)d_in[1];
    float* out = (float*)d_out;
    float* partial = (float*)d_ws;  // 2048 floats = 8 KB

    msl_main<<<NBLOCKS, TPB, 0, stream>>>(pred, targ, partial);
    msl_reduce<<<1, 256, 0, stream>>>(partial, out);
}

// Round 7
// 143.722 us; speedup vs baseline: 1.0778x; 1.0015x over previous
//
#include <hip/hip_runtime.h>

#define B_ROWS 2048
#define S_LEN  8192
#define PER_LANE 16
#define CHUNK (64 * PER_LANE)      // 1024 elements per wave-chunk
#define CPR (S_LEN / CHUNK)        // 8 chunks per row
#define TPB 256
#define WPB 4                      // waves per block -- each wave an INDEPENDENT chunk
#define NCHUNK (B_ROWS * CPR)      // 16384 chunks
#define NBLOCKS (NCHUNK / WPB)     // 4096 blocks
#define HALO 256                   // carry horizon: (1-a)^256 <= 2e-12 for all alphas

// ---- compile-time decay constants ----
constexpr double cpowi(double b, int e) { double r = 1.0; for (int i = 0; i < e; ++i) r *= b; return r; }
constexpr float tof(double x) { return (x < 1.2e-38 && x > -1.2e-38) ? 0.0f : (float)x; }

// Delta-space EMA: du_j = W*du_{j-1} + dx_j  (W = 1-alpha); pd = alpha*du.
#define W0f 0.9f
#define W1f 0.7f
#define W2f 0.4f
#define SE0 0.2f               // 2*alpha (we accumulate 2*h; 0.5 folded into final weights)
#define SE1 0.6f
#define SE2 1.2f
constexpr float NA0 = -(0.1f * 0.1f);   // -alpha^2
constexpr float NA1 = -(0.3f * 0.3f);
constexpr float NA2 = -(0.6f * 0.6f);

// main Kogge-Stone (lane spacing 16 elements); sub-noise steps pruned (r2-r6 absmax 0.0)
constexpr float D0_1 = tof(cpowi(0.9, 16)),  D0_2 = tof(cpowi(0.9, 32));
constexpr float D0_4 = tof(cpowi(0.9, 64)),  D0_8 = tof(cpowi(0.9, 128));
constexpr float D1_1 = tof(cpowi(0.7, 16)),  D1_2 = tof(cpowi(0.7, 32));
constexpr float D2_1 = tof(cpowi(0.4, 16));
// halo Kogge-Stone (lane spacing 4 elements)
constexpr float H0_1 = tof(cpowi(0.9, 4)),   H0_2 = tof(cpowi(0.9, 8));
constexpr float H0_4 = tof(cpowi(0.9, 16)),  H0_8 = tof(cpowi(0.9, 32));
constexpr float H0_16 = tof(cpowi(0.9, 64)), H0_32 = tof(cpowi(0.9, 128));
constexpr float H1_1 = tof(cpowi(0.7, 4)),   H1_2 = tof(cpowi(0.7, 8));
constexpr float H1_4 = tof(cpowi(0.7, 16)),  H1_8 = tof(cpowi(0.7, 32));
constexpr float H1_16 = tof(cpowi(0.7, 64));
constexpr float H2_1 = tof(cpowi(0.4, 4)),   H2_2 = tof(cpowi(0.4, 8));
constexpr float H2_4 = tof(cpowi(0.4, 16));

// log2(1-alpha): chunk carry fold weights (1-a)^(16*lane) = exp2(16*lane*log2(1-a))
#define L2_0 (-0.15200309344504997f)
#define L2_1 (-0.51457317282975830f)
#define L2_2 (-1.32192809488736230f)

__device__ __forceinline__ float scan6(float v, int lane, float d1, float d2, float d4,
                                       float d8, float d16, float d32) {
    float u;
    u = __shfl_up(v, 1);  v += (lane >= 1  ? d1  : 0.0f) * u;
    u = __shfl_up(v, 2);  v += (lane >= 2  ? d2  : 0.0f) * u;
    u = __shfl_up(v, 4);  v += (lane >= 4  ? d4  : 0.0f) * u;
    u = __shfl_up(v, 8);  v += (lane >= 8  ? d8  : 0.0f) * u;
    u = __shfl_up(v, 16); v += (lane >= 16 ? d16 : 0.0f) * u;
    u = __shfl_up(v, 32); v += (lane >= 32 ? d32 : 0.0f) * u;
    return v;
}
__device__ __forceinline__ float scan5(float v, int lane, float d1, float d2, float d4,
                                       float d8, float d16) {
    float u;
    u = __shfl_up(v, 1);  v += (lane >= 1  ? d1  : 0.0f) * u;
    u = __shfl_up(v, 2);  v += (lane >= 2  ? d2  : 0.0f) * u;
    u = __shfl_up(v, 4);  v += (lane >= 4  ? d4  : 0.0f) * u;
    u = __shfl_up(v, 8);  v += (lane >= 8  ? d8  : 0.0f) * u;
    u = __shfl_up(v, 16); v += (lane >= 16 ? d16 : 0.0f) * u;
    return v;
}
__device__ __forceinline__ float scan4(float v, int lane, float d1, float d2, float d4, float d8) {
    float u;
    u = __shfl_up(v, 1); v += (lane >= 1 ? d1 : 0.0f) * u;
    u = __shfl_up(v, 2); v += (lane >= 2 ? d2 : 0.0f) * u;
    u = __shfl_up(v, 4); v += (lane >= 4 ? d4 : 0.0f) * u;
    u = __shfl_up(v, 8); v += (lane >= 8 ? d8 : 0.0f) * u;
    return v;
}
__device__ __forceinline__ float scan3(float v, int lane, float d1, float d2, float d4) {
    float u;
    u = __shfl_up(v, 1); v += (lane >= 1 ? d1 : 0.0f) * u;
    u = __shfl_up(v, 2); v += (lane >= 2 ? d2 : 0.0f) * u;
    u = __shfl_up(v, 4); v += (lane >= 4 ? d4 : 0.0f) * u;
    return v;
}
__device__ __forceinline__ float scan2(float v, int lane, float d1, float d2) {
    float u;
    u = __shfl_up(v, 1); v += (lane >= 1 ? d1 : 0.0f) * u;
    u = __shfl_up(v, 2); v += (lane >= 2 ? d2 : 0.0f) * u;
    return v;
}
__device__ __forceinline__ float scan1(float v, int lane, float d1) {
    float u;
    u = __shfl_up(v, 1); v += (lane >= 1 ? d1 : 0.0f) * u;
    return v;
}

__global__ void __launch_bounds__(TPB, 5) msl_main(const float* __restrict__ pred,
                                                   const float* __restrict__ targ,
                                                   float* __restrict__ partial) {
    const int lane = threadIdx.x & 63;
    const int wave = threadIdx.x >> 6;
    const int gcid = blockIdx.x * WPB + wave;   // global chunk id
    const int row  = gcid >> 3;                 // / CPR
    const int cid  = gcid & (CPR - 1);
    const float* __restrict__ prow = pred + (size_t)row * S_LEN;
    const float* __restrict__ trow = targ + (size_t)row * S_LEN;
    const int co   = cid * CHUNK;
    const int base = co + lane * PER_LANE;

    // dx scratch for j=1..15 (j=0 stays in registers: keeps LDS at 30.7 KB ->
    // 5 blocks/CU instead of 4). Layout [j][lane]: fixed j -> lane-consecutive
    // 4B -> 2 lanes/bank, conflict-free (r6: 0 conflicts).
    __shared__ float dxs[WPB][2][PER_LANE - 1][64];   // 30720 B
    __shared__ float sred[WPB];

    const bool lz     = (lane == 0);
    const bool haloed = (cid != 0);
    const bool head   = (!haloed) && lz;   // owns global element 0 of the row

    // ---- chunk load ----
    float xp[PER_LANE], xt[PER_LANE];
    {
        const float4* p4 = reinterpret_cast<const float4*>(prow + base);
        const float4* t4 = reinterpret_cast<const float4*>(trow + base);
#pragma unroll
        for (int j = 0; j < PER_LANE / 4; ++j) {
            float4 a = p4[j];
            float4 b = t4[j];
            xp[4 * j + 0] = a.x; xp[4 * j + 1] = a.y; xp[4 * j + 2] = a.z; xp[4 * j + 3] = a.w;
            xt[4 * j + 0] = b.x; xt[4 * j + 1] = b.y; xt[4 * j + 2] = b.z; xt[4 * j + 3] = b.w;
        }
    }

    // ---- halo: recompute the chunk carry-in locally (replaces the inter-wave
    // LDS exchange + barrier of r1-r6; truncation weight (1-a)^256 <= 2e-12).
    // Same machinery at spacing 4: lane-local EMA of halo dx + pruned scan;
    // C = lane 63's value = du at element co-1. ----
    float Cp0 = 0.f, Cp1 = 0.f, Cp2 = 0.f, Ct0 = 0.f, Ct1 = 0.f, Ct2 = 0.f;
    float lastp = xp[0], lastt = xt[0];   // row-start default => dx_0 = 0 (head)
    if (haloed) {                          // wave-uniform branch (cid is per-wave)
        float hp[4], ht[4];
        {
            float4 a = *reinterpret_cast<const float4*>(prow + co - HALO + lane * 4);
            float4 b = *reinterpret_cast<const float4*>(trow + co - HALO + lane * 4);
            hp[0] = a.x; hp[1] = a.y; hp[2] = a.z; hp[3] = a.w;
            ht[0] = b.x; ht[1] = b.y; ht[2] = b.z; ht[3] = b.w;
        }
        float php = __shfl_up(hp[3], 1);
        float pht = __shfl_up(ht[3], 1);
        if (lz) { php = hp[0]; pht = ht[0]; }   // oldest halo dx := 0 (weight ~0)

        float Ap0 = 0.f, Ap1 = 0.f, Ap2 = 0.f, At0 = 0.f, At1 = 0.f, At2 = 0.f;
#pragma unroll
        for (int s = 0; s < 4; ++s) {
            float dxp = hp[s] - php; php = hp[s];
            float dxt = ht[s] - pht; pht = ht[s];
            Ap0 = fmaf(W0f, Ap0, dxp);
            Ap1 = fmaf(W1f, Ap1, dxp);
            Ap2 = fmaf(W2f, Ap2, dxp);
            At0 = fmaf(W0f, At0, dxt);
            At1 = fmaf(W1f, At1, dxt);
            At2 = fmaf(W2f, At2, dxt);
        }
        float vh;
        vh = scan6(Ap0, lane, H0_1, H0_2, H0_4, H0_8, H0_16, H0_32); Cp0 = __shfl(vh, 63);
        vh = scan5(Ap1, lane, H1_1, H1_2, H1_4, H1_8, H1_16);        Cp1 = __shfl(vh, 63);
        vh = scan3(Ap2, lane, H2_1, H2_2, H2_4);                     Cp2 = __shfl(vh, 63);
        vh = scan6(At0, lane, H0_1, H0_2, H0_4, H0_8, H0_16, H0_32); Ct0 = __shfl(vh, 63);
        vh = scan5(At1, lane, H1_1, H1_2, H1_4, H1_8, H1_16);        Ct1 = __shfl(vh, 63);
        vh = scan3(At2, lane, H2_1, H2_2, H2_4);                     Ct2 = __shfl(vh, 63);
        lastp = __shfl(hp[3], 63);   // element co-1, for lane 0's first dx
        lastt = __shfl(ht[3], 63);
    }

    // chunk dx boundary: lane l's previous element
    float pvp = __shfl_up(xp[PER_LANE - 1], 1);
    float pvt = __shfl_up(xt[PER_LANE - 1], 1);
    if (lz) { pvp = lastp; pvt = lastt; }

    // ---- pass 1: dx, stage dx (j>=1 to LDS, j=0 in regs), lane-local du-EMA ----
    float dx0p, dx0t;
    float Mp0 = 0.f, Mp1 = 0.f, Mp2 = 0.f, Mt0 = 0.f, Mt1 = 0.f, Mt2 = 0.f;
#pragma unroll
    for (int j = 0; j < PER_LANE; ++j) {
        float dxp = xp[j] - pvp; pvp = xp[j];
        float dxt = xt[j] - pvt; pvt = xt[j];
        if (j == 0) { dx0p = dxp; dx0t = dxt; }
        else        { dxs[wave][0][j - 1][lane] = dxp; dxs[wave][1][j - 1][lane] = dxt; }
        Mp0 = fmaf(W0f, Mp0, dxp);
        Mp1 = fmaf(W1f, Mp1, dxp);
        Mp2 = fmaf(W2f, Mp2, dxp);
        Mt0 = fmaf(W0f, Mt0, dxt);
        Mt1 = fmaf(W1f, Mt1, dxt);
        Mt2 = fmaf(W2f, Mt2, dxt);
    }
    // x dead from here.

    // ---- main scans (spacing 16, pruned as r2-r6) ----
    float vp0 = scan4(Mp0, lane, D0_1, D0_2, D0_4, D0_8);
    float vp1 = scan2(Mp1, lane, D1_1, D1_2);
    float vp2 = scan1(Mp2, lane, D2_1);
    float vt0 = scan4(Mt0, lane, D0_1, D0_2, D0_4, D0_8);
    float vt1 = scan2(Mt1, lane, D1_1, D1_2);
    float vt2 = scan1(Mt2, lane, D2_1);

    // exclusive carry with halo fold: y_l = (l==0) ? C : v_{l-1} + (1-a)^(16l)*C
    const float e  = (float)(PER_LANE * lane);
    const float G0 = exp2f(e * L2_0);
    const float G1 = exp2f(e * L2_1);
    const float G2 = exp2f(e * L2_2);

    float up0 = __shfl_up(vp0, 1), up1 = __shfl_up(vp1, 1), up2 = __shfl_up(vp2, 1);
    float ut0 = __shfl_up(vt0, 1), ut1 = __shfl_up(vt1, 1), ut2 = __shfl_up(vt2, 1);

    float yp0 = lz ? Cp0 : fmaf(G0, Cp0, up0);
    float yp1 = lz ? Cp1 : fmaf(G1, Cp1, up1);
    float yp2 = lz ? Cp2 : fmaf(G2, Cp2, up2);
    float yt0 = lz ? Ct0 : fmaf(G0, Ct0, ut0);
    float yt1 = lz ? Ct1 : fmaf(G1, Ct1, ut1);
    float yt2 = lz ? Ct2 : fmaf(G2, Ct2, ut2);

    // ---- pass 2: du = fma(W, du, dx); huber on scaled deltas.
    // pd = a*dup, td = a*dut: dir<0 <=> dup*dut<0 ; se = a|dup-dut| ;
    // quad = 0.5*max(1 - a^2*dup*dut, 0)^2. Accumulate 2*h. ----
    float acc0 = 0.f, acc1 = 0.f, acc2 = 0.f;
    const float skip = head ? 0.0f : 1.0f;   // no loss term for the row's t=0
#pragma unroll
    for (int j = 0; j < PER_LANE; ++j) {
        float dxp = (j == 0) ? dx0p : dxs[wave][0][j - 1][lane];
        float dxt = (j == 0) ? dx0t : dxs[wave][1][j - 1][lane];
        yp0 = fmaf(W0f, yp0, dxp);
        yt0 = fmaf(W0f, yt0, dxt);
        yp1 = fmaf(W1f, yp1, dxp);
        yt1 = fmaf(W1f, yt1, dxt);
        yp2 = fmaf(W2f, yp2, dxp);
        yt2 = fmaf(W2f, yt2, dxt);

        float m0 = yp0 * yt0, m1 = yp1 * yt1, m2 = yp2 * yt2;
        float se0 = SE0 * fabsf(yp0 - yt0);
        float se1 = SE1 * fabsf(yp1 - yt1);
        float se2 = SE2 * fabsf(yp2 - yt2);
        float mm0 = fmaxf(fmaf(NA0, m0, 1.0f), 0.0f);
        float mm1 = fmaxf(fmaf(NA1, m1, 1.0f), 0.0f);
        float mm2 = fmaxf(fmaf(NA2, m2, 1.0f), 0.0f);
        float h0 = (m0 < 0.0f) ? se0 : mm0 * mm0;
        float h1 = (m1 < 0.0f) ? se1 : mm1 * mm1;
        float h2 = (m2 < 0.0f) ? se2 : mm2 * mm2;
        if (j == 0) { h0 *= skip; h1 *= skip; h2 *= skip; }
        acc0 += h0; acc1 += h1; acc2 += h2;
    }

    // accumulated 2*h -> weights 0.5*{0.5,0.3,0.2}; wave reduce; tiny block sum
    float wacc = 0.25f * acc0 + 0.15f * acc1 + 0.10f * acc2;
#pragma unroll
    for (int o = 32; o > 0; o >>= 1) wacc += __shfl_down(wacc, o);

    if (lz) sred[wave] = wacc;
    __syncthreads();   // the ONLY barrier, at kernel end
    if (threadIdx.x == 0)
        partial[blockIdx.x] = sred[0] + sred[1] + sred[2] + sred[3];
}

__global__ void __launch_bounds__(256) msl_reduce(const float* __restrict__ partial,
                                                  float* __restrict__ out) {
    const int tid = threadIdx.x;
    float v = 0.f;
#pragma unroll
    for (int k = 0; k < NBLOCKS / 256; ++k) v += partial[tid + 256 * k];
#pragma unroll
    for (int o = 32; o > 0; o >>= 1) v += __shfl_down(v, o);
    __shared__ float s[4];
    if ((tid & 63) == 0) s[tid >> 6] = v;
    __syncthreads();
    if (tid == 0)
        out[0] = (s[0] + s[1] + s[2] + s[3]) *
                 (float)(1.0 / ((double)(S_LEN - 1) * (double)B_ROWS));
}

extern "C" void kernel_launch(void* const* d_in, const int* in_sizes, int n_in,
                              void* d_out, int out_size, void* d_ws, size_t ws_size,
                              hipStream_t stream) {
    const float* pred = (const float*)d_in[0];
    const float* targ = (const float*)d_in[1];
    float* out = (float*)d_out;
    float* partial = (float*)d_ws;  // 4096 floats = 16 KB

    msl_main<<<NBLOCKS, TPB, 0, stream>>>(pred, targ, partial);
    msl_reduce<<<1, 256, 0, stream>>>(partial, out);
}